// Round 7
// baseline (322.664 us; speedup 1.0000x reference)
//
#include <hip/hip_runtime.h>
#include <hip/hip_bf16.h>

// Shapes (fixed by the reference)
#define BB 16
#define HH 64
#define WW 64
#define CC 256
#define OH 128
#define OW 128
#define FF 256

typedef __attribute__((ext_vector_type(8))) short bf16x8;
typedef __attribute__((ext_vector_type(4))) float f32x4;

// RNE float -> bf16 bits
__device__ __forceinline__ short f2bf(float x) {
    union { float f; unsigned u; } v; v.f = x;
    unsigned r = v.u + 0x7fffu + ((v.u >> 16) & 1u);
    return (short)(r >> 16);
}

// packed f32x2 -> bf16x2 (1 VALU instr)
__device__ __forceinline__ unsigned cvtpk(float lo, float hi) {
    unsigned r;
    asm("v_cvt_pk_bf16_f32 %0, %1, %2" : "=v"(r) : "v"(lo), "v"(hi));
    return r;
}

// prep: blocks 0..255 transpose pw [c][f] f32 -> pwt [f][c] bf16;
//       block 256 repacks dw [(r*4+s)*256+c] -> dwb [(r*256+c)*4+s] (f32)
__global__ void prep_kernel(const float* __restrict__ pw, const float* __restrict__ dw,
                            short* __restrict__ pwt, float* __restrict__ dwb) {
    if (blockIdx.x < 256) {
        int f = blockIdx.x, c = threadIdx.x;
        pwt[f * CC + c] = f2bf(pw[c * FF + f]);
    } else {
        for (int k = threadIdx.x; k < 4 * 4 * CC; k += 256) {
            int r = k >> 10;
            int rem = k & 1023;
            int s = rem >> 8;
            int c = rem & 255;
            dwb[(r * CC + c) * 4 + s] = dw[(r * 4 + s) * CC + c];
        }
    }
}

__device__ __forceinline__ void tap(float acc[8], const float w[8], const float* xptr) {
    const float4* xp = reinterpret_cast<const float4*>(xptr);
    float4 x0 = xp[0], x1 = xp[1];
    acc[0] += w[0] * x0.x; acc[1] += w[1] * x0.y;
    acc[2] += w[2] * x0.z; acc[3] += w[3] * x0.w;
    acc[4] += w[4] * x1.x; acc[5] += w[5] * x1.y;
    acc[6] += w[6] * x1.z; acc[7] += w[7] * x1.w;
}

// ---------------- Pass 1: depthwise tconv -> tg (bf16 [M][256]), M = B*OH*OW ----
// One block = one output row (b, oh). 256 threads, no LDS, no barriers.
__global__ __launch_bounds__(256, 8)
void dw_kernel(const float* __restrict__ X,
               const float* __restrict__ dwb,
               short* __restrict__ tg) {
    const int tid = threadIdx.x;
    const int blk = blockIdx.x;          // b*OH + oh
    const int oh = blk & (OH - 1);
    const int b  = blk >> 7;

    int r0, r1, i0, i1;
    if (oh & 1) { r0 = 0; i0 = (oh + 1) >> 1; r1 = 2; i1 = (oh - 1) >> 1; }
    else        { r0 = 1; i0 = oh >> 1;       r1 = 3; i1 = (oh >> 1) - 1; }

    const int cg = tid & 31;             // 8-channel group
    const int c0 = cg << 3;
    const int owp = tid >> 5;            // 0..7, ow stride 8
    const int par = owp & 1;

    float w[2][2][8];
    const float4* dwb4 = reinterpret_cast<const float4*>(dwb);
    #pragma unroll
    for (int e = 0; e < 8; ++e) {
        float4 wa = dwb4[r0 * CC + c0 + e];
        float4 wb = dwb4[r1 * CC + c0 + e];
        w[0][0][e] = par ? wa.x : wa.y;
        w[0][1][e] = par ? wa.z : wa.w;
        w[1][0][e] = par ? wb.x : wb.y;
        w[1][1][e] = par ? wb.z : wb.w;
    }

    const bool va0 = (unsigned)i0 < HH;
    const bool va1 = (unsigned)i1 < HH;
    const float* Xr0 = X + (size_t)(b * HH + (va0 ? i0 : 0)) * WW * CC;
    const float* Xr1 = X + (size_t)(b * HH + (va1 ? i1 : 0)) * WW * CC;

    bf16x8* tv = reinterpret_cast<bf16x8*>(tg);
    const size_t mrow = (size_t)blk * OW;

    #pragma unroll
    for (int t8 = 0; t8 < 16; ++t8) {
        const int ow = owp + t8 * 8;
        int je, jo;
        if (par) { je = (ow + 1) >> 1; jo = (ow - 1) >> 1; }
        else     { je = ow >> 1;       jo = (ow >> 1) - 1; }
        const bool vje = (unsigned)je < WW;
        const bool vjo = (unsigned)jo < WW;

        float acc[8];
        #pragma unroll
        for (int e = 0; e < 8; ++e) acc[e] = 0.f;

        if (va0) {
            if (vje) tap(acc, w[0][0], Xr0 + je * CC + c0);
            if (vjo) tap(acc, w[0][1], Xr0 + jo * CC + c0);
        }
        if (va1) {
            if (vje) tap(acc, w[1][0], Xr1 + je * CC + c0);
            if (vjo) tap(acc, w[1][1], Xr1 + jo * CC + c0);
        }

        union { unsigned u[4]; bf16x8 v; } pk;
        pk.u[0] = cvtpk(acc[0], acc[1]);
        pk.u[1] = cvtpk(acc[2], acc[3]);
        pk.u[2] = cvtpk(acc[4], acc[5]);
        pk.u[3] = cvtpk(acc[6], acc[7]);
        tv[(mrow + ow) * 32 + cg] = pk.v;
    }
}

// ---------------- Pass 2: pointwise GEMM out[m][f] = relu(pwt[f][:]·tg[m][:] + bias)
// One block = 64 m-rows x 256 f. 256 threads = 4 waves (one f-block each).
// No LDS, no barriers; A streamed from global, B/bias L2-hot.
__global__ __launch_bounds__(256, 4)
void pw_kernel(const short* __restrict__ tg,
               const short* __restrict__ pwt,
               const float* __restrict__ bias,
               float* __restrict__ out) {
    const int tid  = threadIdx.x;
    const int lane = tid & 63;
    const int cw   = tid >> 6;           // wave 0..3 -> f block
    const int lr   = lane & 15;
    const int lk8  = lane >> 4;          // 0..3
    const size_t m0 = (size_t)blockIdx.x * 64;

    const bf16x8* tv = reinterpret_cast<const bf16x8*>(tg);
    const bf16x8* pv = reinterpret_cast<const bf16x8*>(pwt);

    f32x4 acc[4][4];
    #pragma unroll
    for (int mi = 0; mi < 4; ++mi)
        #pragma unroll
        for (int ni = 0; ni < 4; ++ni)
            acc[mi][ni] = (f32x4){0.f, 0.f, 0.f, 0.f};

    #pragma unroll
    for (int kk = 0; kk < 8; ++kk) {
        const int kg = kk * 4 + lk8;
        bf16x8 af[4], bfr[4];
        #pragma unroll
        for (int mi = 0; mi < 4; ++mi)
            af[mi] = tv[(m0 + mi * 16 + lr) * 32 + kg];
        #pragma unroll
        for (int ni = 0; ni < 4; ++ni)
            bfr[ni] = pv[(cw * 64 + ni * 16 + lr) * 32 + kg];
        #pragma unroll
        for (int mi = 0; mi < 4; ++mi)
            #pragma unroll
            for (int ni = 0; ni < 4; ++ni)
                acc[mi][ni] = __builtin_amdgcn_mfma_f32_16x16x32_bf16(
                    bfr[ni], af[mi], acc[mi][ni], 0, 0, 0);
    }

    #pragma unroll
    for (int ni = 0; ni < 4; ++ni) {
        const int f0 = cw * 64 + ni * 16 + lk8 * 4;
        const f32x4 bv = *reinterpret_cast<const f32x4*>(&bias[f0]);
        #pragma unroll
        for (int mi = 0; mi < 4; ++mi) {
            const size_t m = m0 + mi * 16 + lr;
            f32x4 v = acc[mi][ni] + bv;
            v[0] = v[0] > 0.f ? v[0] : 0.f;
            v[1] = v[1] > 0.f ? v[1] : 0.f;
            v[2] = v[2] > 0.f ? v[2] : 0.f;
            v[3] = v[3] > 0.f ? v[3] : 0.f;
            *reinterpret_cast<f32x4*>(&out[m * FF + f0]) = v;
        }
    }
}

// ---------------- Fallback: improved r1 fused (if ws too small for tg) ----------
__global__ __launch_bounds__(512, 2)
void fused_kernel(const float* __restrict__ X,
                  const float* __restrict__ dwb,
                  const short* __restrict__ pwt,
                  const float* __restrict__ bias,
                  float* __restrict__ out) {
    __shared__ bf16x8 t_lds[OW * 32];    // 64 KiB

    const int tid = threadIdx.x;
    const int blk = blockIdx.x;          // b*OH + oh
    const int oh = blk & (OH - 1);
    const int b  = blk >> 7;

    int r0, r1, i0, i1;
    if (oh & 1) { r0 = 0; i0 = (oh + 1) >> 1; r1 = 2; i1 = (oh - 1) >> 1; }
    else        { r0 = 1; i0 = oh >> 1;       r1 = 3; i1 = (oh >> 1) - 1; }

    {   // phase 1
        const int cg = tid & 31;
        const int c0 = cg << 3;
        const int owp = tid >> 5;        // 0..15, ow stride 16
        const int par = owp & 1;

        float w[2][2][8];
        const float4* dwb4 = reinterpret_cast<const float4*>(dwb);
        #pragma unroll
        for (int e = 0; e < 8; ++e) {
            float4 wa = dwb4[r0 * CC + c0 + e];
            float4 wb = dwb4[r1 * CC + c0 + e];
            w[0][0][e] = par ? wa.x : wa.y;
            w[0][1][e] = par ? wa.z : wa.w;
            w[1][0][e] = par ? wb.x : wb.y;
            w[1][1][e] = par ? wb.z : wb.w;
        }

        const bool va0 = (unsigned)i0 < HH;
        const bool va1 = (unsigned)i1 < HH;
        const float* Xr0 = X + (size_t)(b * HH + (va0 ? i0 : 0)) * WW * CC;
        const float* Xr1 = X + (size_t)(b * HH + (va1 ? i1 : 0)) * WW * CC;

        #pragma unroll
        for (int t8 = 0; t8 < 8; ++t8) {
            const int ow = owp + t8 * 16;
            int je, jo;
            if (par) { je = (ow + 1) >> 1; jo = (ow - 1) >> 1; }
            else     { je = ow >> 1;       jo = (ow >> 1) - 1; }
            const bool vje = (unsigned)je < WW;
            const bool vjo = (unsigned)jo < WW;

            float acc[8];
            #pragma unroll
            for (int e = 0; e < 8; ++e) acc[e] = 0.f;

            if (va0) {
                if (vje) tap(acc, w[0][0], Xr0 + je * CC + c0);
                if (vjo) tap(acc, w[0][1], Xr0 + jo * CC + c0);
            }
            if (va1) {
                if (vje) tap(acc, w[1][0], Xr1 + je * CC + c0);
                if (vjo) tap(acc, w[1][1], Xr1 + jo * CC + c0);
            }

            union { unsigned u[4]; bf16x8 v; } pk;
            pk.u[0] = cvtpk(acc[0], acc[1]);
            pk.u[1] = cvtpk(acc[2], acc[3]);
            pk.u[2] = cvtpk(acc[4], acc[5]);
            pk.u[3] = cvtpk(acc[6], acc[7]);
            t_lds[ow * 32 + (cg ^ (ow & 7))] = pk.v;
        }
    }
    __syncthreads();

    // phase 2: 8 waves = 2 ow-halves x 4 f-blocks
    const int lane = tid & 63;
    const int wid  = tid >> 6;
    const int wr = wid >> 2;             // ow half
    const int wc = wid & 3;              // f block
    const int lr  = lane & 15;
    const int lk8 = lane >> 4;
    const bf16x8* pwt_v = reinterpret_cast<const bf16x8*>(pwt);

    f32x4 acc[4][4];
    #pragma unroll
    for (int mi = 0; mi < 4; ++mi)
        #pragma unroll
        for (int ni = 0; ni < 4; ++ni)
            acc[mi][ni] = (f32x4){0.f, 0.f, 0.f, 0.f};

    #pragma unroll
    for (int kk = 0; kk < 8; ++kk) {
        const int kg = kk * 4 + lk8;
        bf16x8 af[4], bfr[4];
        #pragma unroll
        for (int mi = 0; mi < 4; ++mi) {
            const int row = wr * 64 + mi * 16 + lr;
            af[mi] = t_lds[row * 32 + (kg ^ (row & 7))];
        }
        #pragma unroll
        for (int ni = 0; ni < 4; ++ni)
            bfr[ni] = pwt_v[(wc * 64 + ni * 16 + lr) * 32 + kg];
        #pragma unroll
        for (int mi = 0; mi < 4; ++mi)
            #pragma unroll
            for (int ni = 0; ni < 4; ++ni)
                acc[mi][ni] = __builtin_amdgcn_mfma_f32_16x16x32_bf16(
                    bfr[ni], af[mi], acc[mi][ni], 0, 0, 0);
    }

    float* obase = out + ((size_t)blk * OW + wr * 64) * FF;
    #pragma unroll
    for (int ni = 0; ni < 4; ++ni) {
        const int f0 = wc * 64 + ni * 16 + lk8 * 4;
        const f32x4 bv = *reinterpret_cast<const f32x4*>(&bias[f0]);
        #pragma unroll
        for (int mi = 0; mi < 4; ++mi) {
            const int ow = mi * 16 + lr;
            f32x4 v = acc[mi][ni] + bv;
            v[0] = v[0] > 0.f ? v[0] : 0.f;
            v[1] = v[1] > 0.f ? v[1] : 0.f;
            v[2] = v[2] > 0.f ? v[2] : 0.f;
            v[3] = v[3] > 0.f ? v[3] : 0.f;
            *reinterpret_cast<f32x4*>(&obase[(size_t)ow * FF + f0]) = v;
        }
    }
}

extern "C" void kernel_launch(void* const* d_in, const int* in_sizes, int n_in,
                              void* d_out, int out_size, void* d_ws, size_t ws_size,
                              hipStream_t stream) {
    (void)in_sizes; (void)n_in; (void)out_size;
    const float* X    = (const float*)d_in[0];
    const float* dw   = (const float*)d_in[1];
    const float* pw   = (const float*)d_in[2];
    const float* bias = (const float*)d_in[3];
    float* out = (float*)d_out;

    const size_t TBYTES = (size_t)BB * OH * OW * CC * 2;   // 134,217,728

    if (ws_size >= TBYTES + 131072 + 16384) {
        // two-pass streaming path
        short* tg  = (short*)d_ws;
        short* pwt = (short*)((char*)d_ws + TBYTES);
        float* dwb = (float*)((char*)d_ws + TBYTES + 131072);
        prep_kernel<<<dim3(257), dim3(256), 0, stream>>>(pw, dw, pwt, dwb);
        dw_kernel<<<dim3(BB * OH), dim3(256), 0, stream>>>(X, dwb, tg);
        pw_kernel<<<dim3(BB * OH * OW / 64), dim3(256), 0, stream>>>(tg, pwt, bias, out);
    } else {
        // fused fallback
        short* pwt = (short*)d_ws;
        float* dwb = (float*)((char*)d_ws + 131072);
        prep_kernel<<<dim3(257), dim3(256), 0, stream>>>(pw, dw, pwt, dwb);
        fused_kernel<<<dim3(BB * OH), dim3(512), 0, stream>>>(X, dwb, pwt, bias, out);
    }
}

// Round 8
// 235.352 us; speedup vs baseline: 1.3710x; 1.3710x over previous
//
#include <hip/hip_runtime.h>
#include <hip/hip_bf16.h>

// Shapes (fixed by the reference)
#define BB 16
#define HH 64
#define WW 64
#define CC 256
#define OH 128
#define OW 128
#define FF 256

typedef __attribute__((ext_vector_type(8))) short bf16x8;
typedef __attribute__((ext_vector_type(4))) float f32x4;

// RNE float -> bf16 bits
__device__ __forceinline__ short f2bf(float x) {
    union { float f; unsigned u; } v; v.f = x;
    unsigned r = v.u + 0x7fffu + ((v.u >> 16) & 1u);
    return (short)(r >> 16);
}

// packed f32x2 -> bf16x2 (1 VALU instr)
__device__ __forceinline__ unsigned cvtpk(float lo, float hi) {
    unsigned r;
    asm("v_cvt_pk_bf16_f32 %0, %1, %2" : "=v"(r) : "v"(lo), "v"(hi));
    return r;
}

// prep: blocks 0..255 transpose pw [c][f] f32 -> pwt [f][c] bf16;
//       block 256 repacks dw [(r*4+s)*256+c] -> dwb [(r*256+c)*4+s] (f32)
__global__ void prep_kernel(const float* __restrict__ pw, const float* __restrict__ dw,
                            short* __restrict__ pwt, float* __restrict__ dwb) {
    if (blockIdx.x < 256) {
        int f = blockIdx.x, c = threadIdx.x;
        pwt[f * CC + c] = f2bf(pw[c * FF + f]);
    } else {
        for (int k = threadIdx.x; k < 4 * 4 * CC; k += 256) {
            int r = k >> 10;
            int rem = k & 1023;
            int s = rem >> 8;
            int c = rem & 255;
            dwb[(r * CC + c) * 4 + s] = dw[(r * 4 + s) * CC + c];
        }
    }
}

struct TapData { float4 a, b; };
__device__ __forceinline__ TapData tload(const float* p) {
    const float4* q = reinterpret_cast<const float4*>(p);
    TapData d; d.a = q[0]; d.b = q[1]; return d;
}
__device__ __forceinline__ void tfma(float acc[8], const float w[8], const TapData& d) {
    acc[0] += w[0] * d.a.x; acc[1] += w[1] * d.a.y;
    acc[2] += w[2] * d.a.z; acc[3] += w[3] * d.a.w;
    acc[4] += w[4] * d.b.x; acc[5] += w[5] * d.b.y;
    acc[6] += w[6] * d.b.z; acc[7] += w[7] * d.b.w;
}

// One block = one output row (b, oh). 512 threads.
// Phase 1: depthwise -> t_lds (bf16, swizzled), 2-deep batched tap loads.
// Phase 2: 8 waves (2 ow-halves x 4 f-blocks) MFMA, swapped operands, f32x4 stores.
__global__ __launch_bounds__(512, 4)
void sepconvt_kernel(const float* __restrict__ X,
                     const float* __restrict__ dwb,
                     const short* __restrict__ pwt,
                     const float* __restrict__ bias,
                     float* __restrict__ out) {
    __shared__ bf16x8 t_lds[OW * 32];    // 64 KiB

    const int tid = threadIdx.x;
    // Compact XCD swizzle: physical XCD = blockIdx % 8 (round-robin). Give each
    // XCD a contiguous slab of 256 consecutive (b,oh) rows so X-row reuse
    // (oh +-1..2) stays within one XCD's L2.
    const int work = ((blockIdx.x & 7) << 8) | (blockIdx.x >> 3);
    const int oh = work & (OH - 1);
    const int b  = work >> 7;

    // Row taps: even oh -> (r=1, i=oh/2), (r=3, i=oh/2-1); odd -> (r=0,(oh+1)/2),(r=2,(oh-1)/2)
    int r0, r1, i0, i1;
    if (oh & 1) { r0 = 0; i0 = (oh + 1) >> 1; r1 = 2; i1 = (oh - 1) >> 1; }
    else        { r0 = 1; i0 = oh >> 1;       r1 = 3; i1 = (oh >> 1) - 1; }

    // ---- Phase 1 ----
    {
        const int cg  = tid & 31;        // 8-channel group
        const int c0  = cg << 3;
        const int owp = tid >> 5;        // 0..15, ow stride 16
        const int par = owp & 1;

        const bool va0 = (unsigned)i0 < HH;
        const bool va1 = (unsigned)i1 < HH;

        float w[2][2][8];
        const float4* dwb4 = reinterpret_cast<const float4*>(dwb);
        #pragma unroll
        for (int e = 0; e < 8; ++e) {
            float4 wa = dwb4[r0 * CC + c0 + e];
            float4 wb = dwb4[r1 * CC + c0 + e];
            w[0][0][e] = va0 ? (par ? wa.x : wa.y) : 0.f;
            w[0][1][e] = va0 ? (par ? wa.z : wa.w) : 0.f;
            w[1][0][e] = va1 ? (par ? wb.x : wb.y) : 0.f;
            w[1][1][e] = va1 ? (par ? wb.z : wb.w) : 0.f;
        }

        const float* Xr0 = X + (size_t)(b * HH + (va0 ? i0 : 0)) * WW * CC;
        const float* Xr1 = X + (size_t)(b * HH + (va1 ? i1 : 0)) * WW * CC;

        #pragma unroll
        for (int t4 = 0; t4 < 4; ++t4) {
            const int owA = owp + t4 * 32;
            const int owB = owA + 16;
            int jeA, joA, jeB, joB;
            if (par) { jeA = (owA + 1) >> 1; joA = (owA - 1) >> 1;
                       jeB = (owB + 1) >> 1; joB = (owB - 1) >> 1; }
            else     { jeA = owA >> 1;       joA = (owA >> 1) - 1;
                       jeB = owB >> 1;       joB = (owB >> 1) - 1; }
            const bool vjeA = (unsigned)jeA < WW, vjoA = (unsigned)joA < WW;
            const bool vjeB = (unsigned)jeB < WW, vjoB = (unsigned)joB < WW;
            const int jeAc = vjeA ? jeA : 0, joAc = vjoA ? joA : 0;
            const int jeBc = vjeB ? jeB : 0, joBc = vjoB ? joB : 0;

            // issue all 8 tap loads (2 iterations deep) before consuming
            TapData dA0 = tload(Xr0 + jeAc * CC + c0);
            TapData dA1 = tload(Xr0 + joAc * CC + c0);
            TapData dA2 = tload(Xr1 + jeAc * CC + c0);
            TapData dA3 = tload(Xr1 + joAc * CC + c0);
            TapData dB0 = tload(Xr0 + jeBc * CC + c0);
            TapData dB1 = tload(Xr0 + joBc * CC + c0);
            TapData dB2 = tload(Xr1 + jeBc * CC + c0);
            TapData dB3 = tload(Xr1 + joBc * CC + c0);

            float accA[8], accB[8];
            #pragma unroll
            for (int e = 0; e < 8; ++e) { accA[e] = 0.f; accB[e] = 0.f; }

            if (vjeA) { tfma(accA, w[0][0], dA0); tfma(accA, w[1][0], dA2); }
            if (vjoA) { tfma(accA, w[0][1], dA1); tfma(accA, w[1][1], dA3); }
            if (vjeB) { tfma(accB, w[0][0], dB0); tfma(accB, w[1][0], dB2); }
            if (vjoB) { tfma(accB, w[0][1], dB1); tfma(accB, w[1][1], dB3); }

            union { unsigned u[4]; bf16x8 v; } pkA, pkB;
            pkA.u[0] = cvtpk(accA[0], accA[1]);
            pkA.u[1] = cvtpk(accA[2], accA[3]);
            pkA.u[2] = cvtpk(accA[4], accA[5]);
            pkA.u[3] = cvtpk(accA[6], accA[7]);
            pkB.u[0] = cvtpk(accB[0], accB[1]);
            pkB.u[1] = cvtpk(accB[2], accB[3]);
            pkB.u[2] = cvtpk(accB[4], accB[5]);
            pkB.u[3] = cvtpk(accB[6], accB[7]);
            t_lds[owA * 32 + (cg ^ (owA & 7))] = pkA.v;
            t_lds[owB * 32 + (cg ^ (owB & 7))] = pkB.v;
        }
    }
    __syncthreads();

    // ---- Phase 2: MFMA pointwise, swapped operands: D[f][ow] ----
    const int lane = tid & 63;
    const int wid  = tid >> 6;
    const int wr = wid >> 2;             // ow half (0..1)
    const int wc = wid & 3;              // f block (0..3)
    const int lr  = lane & 15;
    const int lk8 = lane >> 4;
    const bf16x8* pwt_v = reinterpret_cast<const bf16x8*>(pwt);

    f32x4 acc[4][4];                     // [mi(ow)][ni(f)]
    #pragma unroll
    for (int mi = 0; mi < 4; ++mi)
        #pragma unroll
        for (int ni = 0; ni < 4; ++ni)
            acc[mi][ni] = (f32x4){0.f, 0.f, 0.f, 0.f};

    #pragma unroll
    for (int kk = 0; kk < 8; ++kk) {
        const int kg = kk * 4 + lk8;
        bf16x8 af[4], bfr[4];
        #pragma unroll
        for (int mi = 0; mi < 4; ++mi) {
            const int row = wr * 64 + mi * 16 + lr;
            af[mi] = t_lds[row * 32 + (kg ^ (row & 7))];
        }
        #pragma unroll
        for (int ni = 0; ni < 4; ++ni)
            bfr[ni] = pwt_v[(wc * 64 + ni * 16 + lr) * 32 + kg];
        #pragma unroll
        for (int mi = 0; mi < 4; ++mi)
            #pragma unroll
            for (int ni = 0; ni < 4; ++ni)
                acc[mi][ni] = __builtin_amdgcn_mfma_f32_16x16x32_bf16(
                    bfr[ni], af[mi], acc[mi][ni], 0, 0, 0);
    }

    // ---- Epilogue: bias + relu + f32x4 stores (clean lines) ----
    float* obase = out + ((size_t)(b * OH + oh) * OW + wr * 64) * FF;
    #pragma unroll
    for (int ni = 0; ni < 4; ++ni) {
        const int f0 = wc * 64 + ni * 16 + lk8 * 4;
        const f32x4 bv = *reinterpret_cast<const f32x4*>(&bias[f0]);
        #pragma unroll
        for (int mi = 0; mi < 4; ++mi) {
            const int ow = mi * 16 + lr;
            f32x4 v = acc[mi][ni] + bv;
            v[0] = v[0] > 0.f ? v[0] : 0.f;
            v[1] = v[1] > 0.f ? v[1] : 0.f;
            v[2] = v[2] > 0.f ? v[2] : 0.f;
            v[3] = v[3] > 0.f ? v[3] : 0.f;
            *reinterpret_cast<f32x4*>(&obase[(size_t)ow * FF + f0]) = v;
        }
    }
}

extern "C" void kernel_launch(void* const* d_in, const int* in_sizes, int n_in,
                              void* d_out, int out_size, void* d_ws, size_t ws_size,
                              hipStream_t stream) {
    (void)in_sizes; (void)n_in; (void)out_size; (void)ws_size;
    const float* X    = (const float*)d_in[0];
    const float* dw   = (const float*)d_in[1];
    const float* pw   = (const float*)d_in[2];
    const float* bias = (const float*)d_in[3];
    float* out = (float*)d_out;
    short* pwt = (short*)d_ws;                        // 256*256*2 = 128 KiB
    float* dwb = (float*)((char*)d_ws + 131072);      // 4*256*4*4 = 16 KiB

    prep_kernel<<<dim3(257), dim3(256), 0, stream>>>(pw, dw, pwt, dwb);
    sepconvt_kernel<<<dim3(BB * OH), dim3(512), 0, stream>>>(X, dwb, pwt, bias, out);
}

// Round 9
// 164.935 us; speedup vs baseline: 1.9563x; 1.4269x over previous
//
#include <hip/hip_runtime.h>
#include <hip/hip_bf16.h>

// Shapes (fixed by the reference)
#define BB 16
#define HH 64
#define WW 64
#define CC 256
#define OH 128
#define OW 128
#define FF 256

typedef __attribute__((ext_vector_type(8))) short bf16x8;
typedef __attribute__((ext_vector_type(4))) float f32x4;

// RNE float -> bf16 bits
__device__ __forceinline__ short f2bf(float x) {
    union { float f; unsigned u; } v; v.f = x;
    unsigned r = v.u + 0x7fffu + ((v.u >> 16) & 1u);
    return (short)(r >> 16);
}

// packed f32x2 -> bf16x2 (1 VALU instr)
__device__ __forceinline__ unsigned cvtpk(float lo, float hi) {
    unsigned r;
    asm("v_cvt_pk_bf16_f32 %0, %1, %2" : "=v"(r) : "v"(lo), "v"(hi));
    return r;
}

// prep: blocks 0..31 build pwtF = pw in MFMA *fragment-linear* order:
//   entry e = ((wc*8 + kk)*4 + ni)*64 + lane   (bf16x8 per entry)
//   holds pw[c0.. c0+7][f] with f = wc*64+ni*16+(lane&15), c0 = kk*32+(lane>>4)*8
// so a wave's B-fragment load is 64 consecutive 16B entries = one dense 1KB burst.
// Block 32 repacks dw -> dwb [(r*256+c)*4+s] (f32).
__global__ void prep_kernel(const float* __restrict__ pw, const float* __restrict__ dw,
                            short* __restrict__ pwtF, float* __restrict__ dwb) {
    if (blockIdx.x < 32) {
        const int e    = blockIdx.x * 256 + threadIdx.x;
        const int lane = e & 63;
        const int ni   = (e >> 6) & 3;
        const int kk   = (e >> 8) & 7;
        const int wc   = e >> 11;
        const int f    = wc * 64 + ni * 16 + (lane & 15);
        const int c0   = kk * 32 + (lane >> 4) * 8;
        bf16x8 v;
        #pragma unroll
        for (int j = 0; j < 8; ++j) v[j] = f2bf(pw[(size_t)(c0 + j) * FF + f]);
        reinterpret_cast<bf16x8*>(pwtF)[e] = v;
    } else {
        for (int k = threadIdx.x; k < 4 * 4 * CC; k += 256) {
            int r = k >> 10;
            int rem = k & 1023;
            int s = rem >> 8;
            int c = rem & 255;
            dwb[(r * CC + c) * 4 + s] = dw[(r * 4 + s) * CC + c];
        }
    }
}

__device__ __forceinline__ void tap(float acc[8], const float w[8], const float* xptr) {
    const float4* xp = reinterpret_cast<const float4*>(xptr);
    float4 x0 = xp[0], x1 = xp[1];
    acc[0] += w[0] * x0.x; acc[1] += w[1] * x0.y;
    acc[2] += w[2] * x0.z; acc[3] += w[3] * x0.w;
    acc[4] += w[4] * x1.x; acc[5] += w[5] * x1.y;
    acc[6] += w[6] * x1.z; acc[7] += w[7] * x1.w;
}

// One block = one output row (b, oh). 512 threads, no swizzle (r1 geometry).
// Phase 1: depthwise -> t_lds (bf16, swizzled). Phase 2: swapped-operand MFMA
// with fragment-linear (fully coalesced) B loads; f32x4 stores.
__global__ __launch_bounds__(512, 4)
void sepconvt_kernel(const float* __restrict__ X,
                     const float* __restrict__ dwb,
                     const short* __restrict__ pwtF,
                     const float* __restrict__ bias,
                     float* __restrict__ out) {
    __shared__ bf16x8 t_lds[OW * 32];    // 64 KiB

    const int tid = threadIdx.x;
    const int blk = blockIdx.x;          // b*OH + oh
    const int oh = blk & (OH - 1);
    const int b  = blk >> 7;

    // Row taps: even oh -> (r=1, i=oh/2), (r=3, i=oh/2-1); odd -> (r=0,(oh+1)/2),(r=2,(oh-1)/2)
    int r0, r1, i0, i1;
    if (oh & 1) { r0 = 0; i0 = (oh + 1) >> 1; r1 = 2; i1 = (oh - 1) >> 1; }
    else        { r0 = 1; i0 = oh >> 1;       r1 = 3; i1 = (oh >> 1) - 1; }

    // ---- Phase 1: depthwise transposed conv -> t_lds ----
    {
        const int cg  = tid & 31;        // 8-channel group
        const int c0  = cg << 3;
        const int owp = tid >> 5;        // 0..15, ow stride 16
        const int par = owp & 1;

        float w[2][2][8];
        const float4* dwb4 = reinterpret_cast<const float4*>(dwb);
        #pragma unroll
        for (int e = 0; e < 8; ++e) {
            float4 wa = dwb4[r0 * CC + c0 + e];
            float4 wb = dwb4[r1 * CC + c0 + e];
            w[0][0][e] = par ? wa.x : wa.y;
            w[0][1][e] = par ? wa.z : wa.w;
            w[1][0][e] = par ? wb.x : wb.y;
            w[1][1][e] = par ? wb.z : wb.w;
        }

        const bool va0 = (unsigned)i0 < HH;
        const bool va1 = (unsigned)i1 < HH;
        const float* Xr0 = X + (size_t)(b * HH + (va0 ? i0 : 0)) * WW * CC;
        const float* Xr1 = X + (size_t)(b * HH + (va1 ? i1 : 0)) * WW * CC;

        #pragma unroll 2
        for (int t = 0; t < 8; ++t) {
            const int ow = owp + t * 16;
            int je, jo;
            if (par) { je = (ow + 1) >> 1; jo = (ow - 1) >> 1; }
            else     { je = ow >> 1;       jo = (ow >> 1) - 1; }
            const bool vje = (unsigned)je < WW;
            const bool vjo = (unsigned)jo < WW;

            float acc[8];
            #pragma unroll
            for (int e = 0; e < 8; ++e) acc[e] = 0.f;

            if (va0) {
                if (vje) tap(acc, w[0][0], Xr0 + je * CC + c0);
                if (vjo) tap(acc, w[0][1], Xr0 + jo * CC + c0);
            }
            if (va1) {
                if (vje) tap(acc, w[1][0], Xr1 + je * CC + c0);
                if (vjo) tap(acc, w[1][1], Xr1 + jo * CC + c0);
            }

            union { unsigned u[4]; bf16x8 v; } pk;
            pk.u[0] = cvtpk(acc[0], acc[1]);
            pk.u[1] = cvtpk(acc[2], acc[3]);
            pk.u[2] = cvtpk(acc[4], acc[5]);
            pk.u[3] = cvtpk(acc[6], acc[7]);
            t_lds[ow * 32 + (cg ^ (ow & 7))] = pk.v;
        }
    }
    __syncthreads();

    // ---- Phase 2: MFMA pointwise, swapped operands: D[f][ow] ----
    const int lane = tid & 63;
    const int wid  = tid >> 6;
    const int wr = wid >> 2;             // ow half (0..1)
    const int wc = wid & 3;              // f block (0..3)
    const int lr  = lane & 15;
    const int lk8 = lane >> 4;
    // wave-local fragment-linear B base: entries [wc][kk][ni][lane]
    const bf16x8* pvF = reinterpret_cast<const bf16x8*>(pwtF) + (size_t)wc * 2048 + lane;

    f32x4 acc[4][4];                     // [mi(ow)][ni(f)]
    #pragma unroll
    for (int mi = 0; mi < 4; ++mi)
        #pragma unroll
        for (int ni = 0; ni < 4; ++ni)
            acc[mi][ni] = (f32x4){0.f, 0.f, 0.f, 0.f};

    #pragma unroll
    for (int kk = 0; kk < 8; ++kk) {
        const int kg = kk * 4 + lk8;
        bf16x8 af[4], bfr[4];
        #pragma unroll
        for (int mi = 0; mi < 4; ++mi) {
            const int row = wr * 64 + mi * 16 + lr;
            af[mi] = t_lds[row * 32 + (kg ^ (row & 7))];
        }
        #pragma unroll
        for (int ni = 0; ni < 4; ++ni)
            bfr[ni] = pvF[(kk * 4 + ni) * 64];   // dense 1KB wave burst
        #pragma unroll
        for (int mi = 0; mi < 4; ++mi)
            #pragma unroll
            for (int ni = 0; ni < 4; ++ni)
                acc[mi][ni] = __builtin_amdgcn_mfma_f32_16x16x32_bf16(
                    bfr[ni], af[mi], acc[mi][ni], 0, 0, 0);
    }

    // ---- Epilogue: bias + relu + f32x4 stores ----
    float* obase = out + ((size_t)(b * OH + oh) * OW + wr * 64) * FF;
    #pragma unroll
    for (int ni = 0; ni < 4; ++ni) {
        const int f0 = wc * 64 + ni * 16 + lk8 * 4;
        const f32x4 bv = *reinterpret_cast<const f32x4*>(&bias[f0]);
        #pragma unroll
        for (int mi = 0; mi < 4; ++mi) {
            const int ow = mi * 16 + lr;
            f32x4 v = acc[mi][ni] + bv;
            v[0] = v[0] > 0.f ? v[0] : 0.f;
            v[1] = v[1] > 0.f ? v[1] : 0.f;
            v[2] = v[2] > 0.f ? v[2] : 0.f;
            v[3] = v[3] > 0.f ? v[3] : 0.f;
            *reinterpret_cast<f32x4*>(&obase[(size_t)ow * FF + f0]) = v;
        }
    }
}

extern "C" void kernel_launch(void* const* d_in, const int* in_sizes, int n_in,
                              void* d_out, int out_size, void* d_ws, size_t ws_size,
                              hipStream_t stream) {
    (void)in_sizes; (void)n_in; (void)out_size; (void)ws_size;
    const float* X    = (const float*)d_in[0];
    const float* dw   = (const float*)d_in[1];
    const float* pw   = (const float*)d_in[2];
    const float* bias = (const float*)d_in[3];
    float* out = (float*)d_out;
    short* pwtF = (short*)d_ws;                       // 8192 entries * 16B = 128 KiB
    float* dwb  = (float*)((char*)d_ws + 131072);     // 16 KiB

    prep_kernel<<<dim3(33), dim3(256), 0, stream>>>(pw, dw, pwtF, dwb);
    sepconvt_kernel<<<dim3(BB * OH), dim3(512), 0, stream>>>(X, dwb, pwtF, bias, out);
}